// Round 6
// baseline (194.094 us; speedup 1.0000x reference)
//
#include <hip/hip_runtime.h>

// Problem constants (match reference)
#define T_DIM 4096
#define B_DIM 256
// N_OBS=64, H=8, N_ACT=18

// ---------------------------------------------------------------------------
// Kernel A: fused MLP  states(B,T,64) -> x1(4) -> x2(B,T,8), relu
// LDS-staged fully-coalesced reads (verified R4; near traffic floor).
// ---------------------------------------------------------------------------
__global__ __launch_bounds__(256) void mlp_kernel(
    const float* __restrict__ states,
    const float* __restrict__ W1, const float* __restrict__ b1,
    const float* __restrict__ W2, const float* __restrict__ b2,
    float* __restrict__ x2out)
{
    __shared__ float4 w1s4[4][16];      // W1 rows as float4
    __shared__ float  w2s[8][4];
    __shared__ float  b1s[4];
    __shared__ float  b2s[8];
    __shared__ float4 stage[4][16 * 17]; // per-wave 16 rows, stride 17 slots

    int tid = threadIdx.x;
    ((float*)w1s4)[tid] = W1[tid];              // 256 floats
    if (tid < 32) ((float*)w2s)[tid] = W2[tid];
    if (tid < 4)  b1s[tid] = b1[tid];
    if (tid >= 8 && tid < 16) b2s[tid - 8] = b2[tid - 8];

    int w = tid >> 6;        // wave 0..3
    int l = tid & 63;        // lane

    // stage 16 rows per wave: 4 contiguous 1KB wave-loads
    const float4* src4 = (const float4*)states;
    size_t base_f4 = ((size_t)blockIdx.x * 64 + (size_t)w * 16) * 16;
#pragma unroll
    for (int k = 0; k < 4; ++k) {
        int idx = k * 64 + l;            // 0..255 within the 16-row tile
        int row = idx >> 4, m = idx & 15;
        stage[w][row * 17 + m] = src4[base_f4 + idx];
    }
    __syncthreads();

    // compute: 4 lanes per row, lane q owns obs [q*16, q*16+16)
    int rl = l >> 2;         // row within wave tile 0..15
    int q  = l & 3;
    const float4* rowp = &stage[w][rl * 17];

    float a0 = 0.f, a1 = 0.f, a2 = 0.f, a3 = 0.f;
#pragma unroll
    for (int kk = 0; kk < 4; ++kk) {
        float4 v = rowp[q * 4 + kk];
        float4 w0 = w1s4[0][q * 4 + kk];
        float4 w1v = w1s4[1][q * 4 + kk];
        float4 w2v = w1s4[2][q * 4 + kk];
        float4 w3v = w1s4[3][q * 4 + kk];
        a0 = fmaf(v.x, w0.x, a0); a0 = fmaf(v.y, w0.y, a0);
        a0 = fmaf(v.z, w0.z, a0); a0 = fmaf(v.w, w0.w, a0);
        a1 = fmaf(v.x, w1v.x, a1); a1 = fmaf(v.y, w1v.y, a1);
        a1 = fmaf(v.z, w1v.z, a1); a1 = fmaf(v.w, w1v.w, a1);
        a2 = fmaf(v.x, w2v.x, a2); a2 = fmaf(v.y, w2v.y, a2);
        a2 = fmaf(v.z, w2v.z, a2); a2 = fmaf(v.w, w2v.w, a2);
        a3 = fmaf(v.x, w3v.x, a3); a3 = fmaf(v.y, w3v.y, a3);
        a3 = fmaf(v.z, w3v.z, a3); a3 = fmaf(v.w, w3v.w, a3);
    }
    // butterfly reduce across the 4 lanes of this row
    a0 += __shfl_xor(a0, 1, 64); a1 += __shfl_xor(a1, 1, 64);
    a2 += __shfl_xor(a2, 1, 64); a3 += __shfl_xor(a3, 1, 64);
    a0 += __shfl_xor(a0, 2, 64); a1 += __shfl_xor(a1, 2, 64);
    a2 += __shfl_xor(a2, 2, 64); a3 += __shfl_xor(a3, 2, 64);

    a0 = fmaxf(a0 + b1s[0], 0.f);
    a1 = fmaxf(a1 + b1s[1], 0.f);
    a2 = fmaxf(a2 + b1s[2], 0.f);
    a3 = fmaxf(a3 + b1s[3], 0.f);

    // lane q produces x2 elements 2q, 2q+1
    int h0 = 2 * q, h1 = 2 * q + 1;
    float s0 = b2s[h0];
    s0 = fmaf(a0, w2s[h0][0], s0); s0 = fmaf(a1, w2s[h0][1], s0);
    s0 = fmaf(a2, w2s[h0][2], s0); s0 = fmaf(a3, w2s[h0][3], s0);
    float s1 = b2s[h1];
    s1 = fmaf(a0, w2s[h1][0], s1); s1 = fmaf(a1, w2s[h1][1], s1);
    s1 = fmaf(a2, w2s[h1][2], s1); s1 = fmaf(a3, w2s[h1][3], s1);
    s0 = fmaxf(s0, 0.f);
    s1 = fmaxf(s1, 0.f);

    size_t r = (size_t)blockIdx.x * 64 + (size_t)w * 16 + rl;
    ((float2*)x2out)[r * 4 + q] = make_float2(s0, s1);
}

// ---------------------------------------------------------------------------
// Kernel B: LSTM scan over b (256 steps), 4096 independent t-columns.
// 8 lanes per column: lane j owns gates (i,f,g,o) of output element j —
// no gate gather. Only cross-lane op: h-broadcast = 8 shfls per wave-step
// shared by 8 columns (1 DS op per column-step; was 12).
// Heads fused: lane j -> actions j, 8+j; lane 0/1 -> 16/17; lane 2 -> value.
// NO LDS in this kernel (same-wave LDS write->read convicted in R1/R5).
// ---------------------------------------------------------------------------
__global__ __launch_bounds__(64) void lstm_head_kernel(
    const float* __restrict__ x2,
    const int* __restrict__ dones,
    const float* __restrict__ hx,
    const float* __restrict__ Wih, const float* __restrict__ bih,
    const float* __restrict__ Whh, const float* __restrict__ bhh,
    const float* __restrict__ Wa, const float* __restrict__ ba,
    const float* __restrict__ Wv, const float* __restrict__ bv,
    float* __restrict__ out)
{
    int lane = threadIdx.x;      // 0..63
    int col  = lane >> 3;        // 0..7 column within wave
    int j    = lane & 7;         // output element owned by this lane
    int gb   = lane & 56;        // 8-lane group base
    int t    = blockIdx.x * 8 + col;

    // gate weights: rows j, 8+j, 16+j, 24+j of Wih / Whh
    float wI[8], wF[8], wG[8], wO[8], uI[8], uF[8], uG[8], uO[8];
#pragma unroll
    for (int k = 0; k < 8; ++k) {
        wI[k] = Wih[j * 8 + k];        uI[k] = Whh[j * 8 + k];
        wF[k] = Wih[(8 + j) * 8 + k];  uF[k] = Whh[(8 + j) * 8 + k];
        wG[k] = Wih[(16 + j) * 8 + k]; uG[k] = Whh[(16 + j) * 8 + k];
        wO[k] = Wih[(24 + j) * 8 + k]; uO[k] = Whh[(24 + j) * 8 + k];
    }
    float bI = bih[j]      + bhh[j];
    float bF = bih[8 + j]  + bhh[8 + j];
    float bG = bih[16 + j] + bhh[16 + j];
    float bO = bih[24 + j] + bhh[24 + j];

    // head weights
    float hw0[8], hw1[8], hw2[8];
    float hb0 = ba[j], hb1 = ba[8 + j], hb2 = 0.f;
#pragma unroll
    for (int k = 0; k < 8; ++k) {
        hw0[k] = Wa[j * 8 + k];
        hw1[k] = Wa[(8 + j) * 8 + k];
        hw2[k] = 0.f;
    }
    if (j < 2) {
#pragma unroll
        for (int k = 0; k < 8; ++k) hw2[k] = Wa[(16 + j) * 8 + k];
        hb2 = ba[16 + j];
    } else if (j == 2) {
#pragma unroll
        for (int k = 0; k < 8; ++k) hw2[k] = Wv[k];
        hb2 = bv[0];
    }

    // initial carry: h = hx[0][t][:], c = hx[1][t][j]
    float h[8];
#pragma unroll
    for (int k = 0; k < 8; ++k) h[k] = hx[t * 8 + k];
    float c = hx[T_DIM * 8 + t * 8 + j];

    float* outA = out + (size_t)t * 18;                       // (b*T+t)*18, b=0
    float* outV = out + (size_t)18 * B_DIM * T_DIM + t;       // values block

    // 4-deep prefetch (named registers only)
    int d0, d1, d2, d3;
    float4 xa0, xb0, xa1, xb1, xa2, xb2, xa3, xb3;
    {
        const float4* xp;
#define PF(I) \
        d##I = dones[(size_t)(I) * T_DIM + t]; \
        xp = (const float4*)(x2 + ((size_t)(I) * T_DIM + t) * 8); \
        xa##I = xp[0]; xb##I = xp[1];
        PF(0) PF(1) PF(2) PF(3)
#undef PF
    }

#define LSTM_STEP(BCUR, DPF, XA, XB)                                           \
    {                                                                          \
        int   done = DPF;                                                      \
        float4 va = XA, vb = XB;                                               \
        int bp = (BCUR) + 4;                                                   \
        if (bp < B_DIM) {                                                      \
            DPF = dones[(size_t)bp * T_DIM + t];                               \
            const float4* xp = (const float4*)(x2 + ((size_t)bp * T_DIM + t) * 8); \
            XA = xp[0]; XB = xp[1];                                            \
        }                                                                      \
        /* x-part of the 4 gates (independent chains) */                       \
        float gi = bI, gf = bF, gg = bG, go = bO;                              \
        gi = fmaf(va.x, wI[0], gi); gi = fmaf(va.y, wI[1], gi);                \
        gi = fmaf(va.z, wI[2], gi); gi = fmaf(va.w, wI[3], gi);                \
        gi = fmaf(vb.x, wI[4], gi); gi = fmaf(vb.y, wI[5], gi);                \
        gi = fmaf(vb.z, wI[6], gi); gi = fmaf(vb.w, wI[7], gi);                \
        gf = fmaf(va.x, wF[0], gf); gf = fmaf(va.y, wF[1], gf);                \
        gf = fmaf(va.z, wF[2], gf); gf = fmaf(va.w, wF[3], gf);                \
        gf = fmaf(vb.x, wF[4], gf); gf = fmaf(vb.y, wF[5], gf);                \
        gf = fmaf(vb.z, wF[6], gf); gf = fmaf(vb.w, wF[7], gf);                \
        gg = fmaf(va.x, wG[0], gg); gg = fmaf(va.y, wG[1], gg);                \
        gg = fmaf(va.z, wG[2], gg); gg = fmaf(va.w, wG[3], gg);                \
        gg = fmaf(vb.x, wG[4], gg); gg = fmaf(vb.y, wG[5], gg);                \
        gg = fmaf(vb.z, wG[6], gg); gg = fmaf(vb.w, wG[7], gg);                \
        go = fmaf(va.x, wO[0], go); go = fmaf(va.y, wO[1], go);                \
        go = fmaf(va.z, wO[2], go); go = fmaf(va.w, wO[3], go);                \
        go = fmaf(vb.x, wO[4], go); go = fmaf(vb.y, wO[5], go);                \
        go = fmaf(vb.z, wO[6], go); go = fmaf(vb.w, wO[7], go);                \
        /* h-part */                                                           \
        float dI = h[0] * uI[0], dF = h[0] * uF[0];                            \
        float dG = h[0] * uG[0], dO = h[0] * uO[0];                            \
        dI = fmaf(h[1], uI[1], dI); dF = fmaf(h[1], uF[1], dF);                \
        dG = fmaf(h[1], uG[1], dG); dO = fmaf(h[1], uO[1], dO);                \
        dI = fmaf(h[2], uI[2], dI); dF = fmaf(h[2], uF[2], dF);                \
        dG = fmaf(h[2], uG[2], dG); dO = fmaf(h[2], uO[2], dO);                \
        dI = fmaf(h[3], uI[3], dI); dF = fmaf(h[3], uF[3], dF);                \
        dG = fmaf(h[3], uG[3], dG); dO = fmaf(h[3], uO[3], dO);                \
        dI = fmaf(h[4], uI[4], dI); dF = fmaf(h[4], uF[4], dF);                \
        dG = fmaf(h[4], uG[4], dG); dO = fmaf(h[4], uO[4], dO);                \
        dI = fmaf(h[5], uI[5], dI); dF = fmaf(h[5], uF[5], dF);                \
        dG = fmaf(h[5], uG[5], dG); dO = fmaf(h[5], uO[5], dO);                \
        dI = fmaf(h[6], uI[6], dI); dF = fmaf(h[6], uF[6], dF);                \
        dG = fmaf(h[6], uG[6], dG); dO = fmaf(h[6], uO[6], dO);                \
        dI = fmaf(h[7], uI[7], dI); dF = fmaf(h[7], uF[7], dF);                \
        dG = fmaf(h[7], uG[7], dG); dO = fmaf(h[7], uO[7], dO);                \
        float GI = done ? gi : (gi + dI);                                      \
        float GF = done ? gf : (gf + dF);                                      \
        float GG = done ? gg : (gg + dG);                                      \
        float GO = done ? go : (go + dO);                                      \
        c = done ? 0.f : c;                                                    \
        float i_ = 1.f / (1.f + __expf(-GI));                                  \
        float f_ = 1.f / (1.f + __expf(-GF));                                  \
        float g_ = 2.f / (1.f + __expf(-2.f * GG)) - 1.f;                      \
        float o_ = 1.f / (1.f + __expf(-GO));                                  \
        float c2 = fmaf(f_, c, i_ * g_);                                       \
        c = c2;                                                                \
        float th = 2.f / (1.f + __expf(-2.f * c2)) - 1.f;                      \
        float h2 = o_ * th;                                                    \
        h[0] = __shfl(h2, gb | 0, 64);                                         \
        h[1] = __shfl(h2, gb | 1, 64);                                         \
        h[2] = __shfl(h2, gb | 2, 64);                                         \
        h[3] = __shfl(h2, gb | 3, 64);                                         \
        h[4] = __shfl(h2, gb | 4, 64);                                         \
        h[5] = __shfl(h2, gb | 5, 64);                                         \
        h[6] = __shfl(h2, gb | 6, 64);                                         \
        h[7] = __shfl(h2, gb | 7, 64);                                         \
        float o0 = hb0, o1 = hb1, o2 = hb2;                                    \
        o0 = fmaf(h[0], hw0[0], o0); o1 = fmaf(h[0], hw1[0], o1);              \
        o2 = fmaf(h[0], hw2[0], o2);                                           \
        o0 = fmaf(h[1], hw0[1], o0); o1 = fmaf(h[1], hw1[1], o1);              \
        o2 = fmaf(h[1], hw2[1], o2);                                           \
        o0 = fmaf(h[2], hw0[2], o0); o1 = fmaf(h[2], hw1[2], o1);              \
        o2 = fmaf(h[2], hw2[2], o2);                                           \
        o0 = fmaf(h[3], hw0[3], o0); o1 = fmaf(h[3], hw1[3], o1);              \
        o2 = fmaf(h[3], hw2[3], o2);                                           \
        o0 = fmaf(h[4], hw0[4], o0); o1 = fmaf(h[4], hw1[4], o1);              \
        o2 = fmaf(h[4], hw2[4], o2);                                           \
        o0 = fmaf(h[5], hw0[5], o0); o1 = fmaf(h[5], hw1[5], o1);              \
        o2 = fmaf(h[5], hw2[5], o2);                                           \
        o0 = fmaf(h[6], hw0[6], o0); o1 = fmaf(h[6], hw1[6], o1);              \
        o2 = fmaf(h[6], hw2[6], o2);                                           \
        o0 = fmaf(h[7], hw0[7], o0); o1 = fmaf(h[7], hw1[7], o1);              \
        o2 = fmaf(h[7], hw2[7], o2);                                           \
        outA[j] = o0;                                                          \
        outA[8 + j] = o1;                                                      \
        if (j < 2) outA[16 + j] = o2;                                          \
        else if (j == 2) *outV = o2;                                           \
        outA += (size_t)T_DIM * 18;                                            \
        outV += T_DIM;                                                         \
    }

    for (int b0 = 0; b0 < B_DIM; b0 += 4) {
        LSTM_STEP(b0 + 0, d0, xa0, xb0);
        LSTM_STEP(b0 + 1, d1, xa1, xb1);
        LSTM_STEP(b0 + 2, d2, xa2, xb2);
        LSTM_STEP(b0 + 3, d3, xa3, xb3);
    }
#undef LSTM_STEP
}

// ---------------------------------------------------------------------------
extern "C" void kernel_launch(void* const* d_in, const int* in_sizes, int n_in,
                              void* d_out, int out_size, void* d_ws, size_t ws_size,
                              hipStream_t stream) {
    (void)in_sizes; (void)n_in; (void)out_size; (void)ws_size;
    const float* states = (const float*)d_in[0];
    const int*   dones  = (const int*)d_in[1];
    const float* hx     = (const float*)d_in[2];
    const float* W1     = (const float*)d_in[3];
    const float* b1     = (const float*)d_in[4];
    const float* W2     = (const float*)d_in[5];
    const float* b2     = (const float*)d_in[6];
    const float* Wih    = (const float*)d_in[7];
    const float* bih    = (const float*)d_in[8];
    const float* Whh    = (const float*)d_in[9];
    const float* bhh    = (const float*)d_in[10];
    const float* Wa     = (const float*)d_in[11];
    const float* ba     = (const float*)d_in[12];
    const float* Wv     = (const float*)d_in[13];
    const float* bv     = (const float*)d_in[14];
    float* out = (float*)d_out;
    float* x2buf = (float*)d_ws;   // B*T*8 floats = 32 MiB scratch

    mlp_kernel<<<(B_DIM * T_DIM) / 64, 256, 0, stream>>>(states, W1, b1, W2, b2, x2buf);
    lstm_head_kernel<<<T_DIM / 8, 64, 0, stream>>>(x2buf, dones, hx, Wih, bih, Whh, bhh,
                                                   Wa, ba, Wv, bv, out);
}

// Round 7
// 190.313 us; speedup vs baseline: 1.0199x; 1.0199x over previous
//
#include <hip/hip_runtime.h>

// Problem constants (match reference)
#define T_DIM 4096
#define B_DIM 256
// N_OBS=64, H=8, N_ACT=18

// ws layout: [0, 32MiB) x2t  float, [tb][b][ti][8]  (tb=t>>3, ti=t&7)
//            [32MiB, 36MiB) dones_t int, [tb][b][ti]
#define X2T_FLOATS (8u * 1024u * 1024u)

// ---------------------------------------------------------------------------
// Kernel A: fused MLP  states(B,T,64) -> x1(4) -> x2t (transposed layout)
// LDS-staged fully-coalesced reads (verified R4). Also stages dones_t.
// ---------------------------------------------------------------------------
__global__ __launch_bounds__(256) void mlp_kernel(
    const float* __restrict__ states,
    const int* __restrict__ dones,
    const float* __restrict__ W1, const float* __restrict__ b1,
    const float* __restrict__ W2, const float* __restrict__ b2,
    float* __restrict__ x2t, int* __restrict__ dones_t)
{
    __shared__ float4 w1s4[4][16];      // W1 rows as float4
    __shared__ float  w2s[8][4];
    __shared__ float  b1s[4];
    __shared__ float  b2s[8];
    __shared__ float4 stage[4][16 * 17]; // per-wave 16 rows, stride 17 slots

    int tid = threadIdx.x;
    ((float*)w1s4)[tid] = W1[tid];              // 256 floats
    if (tid < 32) ((float*)w2s)[tid] = W2[tid];
    if (tid < 4)  b1s[tid] = b1[tid];
    if (tid >= 8 && tid < 16) b2s[tid - 8] = b2[tid - 8];

    // stage transposed dones: this block's 64 rows (same b for all 64)
    if (tid < 64) {
        int r2 = blockIdx.x * 64 + tid;
        int b = r2 >> 12, t = r2 & 4095;
        dones_t[(size_t)(t >> 3) * (B_DIM * 8) + b * 8 + (t & 7)] = dones[r2];
    }

    int w = tid >> 6;        // wave 0..3
    int l = tid & 63;        // lane

    // stage 16 rows per wave: 4 contiguous 1KB wave-loads
    const float4* src4 = (const float4*)states;
    size_t base_f4 = ((size_t)blockIdx.x * 64 + (size_t)w * 16) * 16;
#pragma unroll
    for (int k = 0; k < 4; ++k) {
        int idx = k * 64 + l;            // 0..255 within the 16-row tile
        int row = idx >> 4, m = idx & 15;
        stage[w][row * 17 + m] = src4[base_f4 + idx];
    }
    __syncthreads();

    // compute: 4 lanes per row, lane q owns obs [q*16, q*16+16)
    int rl = l >> 2;         // row within wave tile 0..15
    int q  = l & 3;
    const float4* rowp = &stage[w][rl * 17];

    float a0 = 0.f, a1 = 0.f, a2 = 0.f, a3 = 0.f;
#pragma unroll
    for (int kk = 0; kk < 4; ++kk) {
        float4 v = rowp[q * 4 + kk];
        float4 w0 = w1s4[0][q * 4 + kk];
        float4 w1v = w1s4[1][q * 4 + kk];
        float4 w2v = w1s4[2][q * 4 + kk];
        float4 w3v = w1s4[3][q * 4 + kk];
        a0 = fmaf(v.x, w0.x, a0); a0 = fmaf(v.y, w0.y, a0);
        a0 = fmaf(v.z, w0.z, a0); a0 = fmaf(v.w, w0.w, a0);
        a1 = fmaf(v.x, w1v.x, a1); a1 = fmaf(v.y, w1v.y, a1);
        a1 = fmaf(v.z, w1v.z, a1); a1 = fmaf(v.w, w1v.w, a1);
        a2 = fmaf(v.x, w2v.x, a2); a2 = fmaf(v.y, w2v.y, a2);
        a2 = fmaf(v.z, w2v.z, a2); a2 = fmaf(v.w, w2v.w, a2);
        a3 = fmaf(v.x, w3v.x, a3); a3 = fmaf(v.y, w3v.y, a3);
        a3 = fmaf(v.z, w3v.z, a3); a3 = fmaf(v.w, w3v.w, a3);
    }
    // butterfly reduce across the 4 lanes of this row
    a0 += __shfl_xor(a0, 1, 64); a1 += __shfl_xor(a1, 1, 64);
    a2 += __shfl_xor(a2, 1, 64); a3 += __shfl_xor(a3, 1, 64);
    a0 += __shfl_xor(a0, 2, 64); a1 += __shfl_xor(a1, 2, 64);
    a2 += __shfl_xor(a2, 2, 64); a3 += __shfl_xor(a3, 2, 64);

    a0 = fmaxf(a0 + b1s[0], 0.f);
    a1 = fmaxf(a1 + b1s[1], 0.f);
    a2 = fmaxf(a2 + b1s[2], 0.f);
    a3 = fmaxf(a3 + b1s[3], 0.f);

    // lane q produces x2 elements 2q, 2q+1
    int h0 = 2 * q, h1 = 2 * q + 1;
    float s0 = b2s[h0];
    s0 = fmaf(a0, w2s[h0][0], s0); s0 = fmaf(a1, w2s[h0][1], s0);
    s0 = fmaf(a2, w2s[h0][2], s0); s0 = fmaf(a3, w2s[h0][3], s0);
    float s1 = b2s[h1];
    s1 = fmaf(a0, w2s[h1][0], s1); s1 = fmaf(a1, w2s[h1][1], s1);
    s1 = fmaf(a2, w2s[h1][2], s1); s1 = fmaf(a3, w2s[h1][3], s1);
    s0 = fmaxf(s0, 0.f);
    s1 = fmaxf(s1, 0.f);

    // transposed write: float2 index = tb*8192 + b*32 + ti*4 + q
    int r = blockIdx.x * 64 + w * 16 + rl;
    int b = r >> 12, t = r & 4095;
    size_t f2i = (size_t)(t >> 3) * 8192 + (size_t)b * 32 + (t & 7) * 4 + q;
    ((float2*)x2t)[f2i] = make_float2(s0, s1);
}

// ---------------------------------------------------------------------------
// Kernel B: LSTM scan over b (256 steps), 4096 independent t-columns.
// 8 lanes per column; h-broadcast via shfl (verified R6). Streams are
// contiguous-sequential (transposed staging); prefetch 8-deep, UNconditional
// (clamped index) so the compiler can count vmcnt instead of draining.
// ---------------------------------------------------------------------------
__global__ __launch_bounds__(64) void lstm_head_kernel(
    const float* __restrict__ x2t,
    const int* __restrict__ dones_t,
    const float* __restrict__ hx,
    const float* __restrict__ Wih, const float* __restrict__ bih,
    const float* __restrict__ Whh, const float* __restrict__ bhh,
    const float* __restrict__ Wa, const float* __restrict__ ba,
    const float* __restrict__ Wv, const float* __restrict__ bv,
    float* __restrict__ out)
{
    int lane = threadIdx.x;      // 0..63
    int col  = lane >> 3;        // 0..7 column within wave
    int j    = lane & 7;         // output element owned by this lane
    int gb   = lane & 56;        // 8-lane group base
    int t    = blockIdx.x * 8 + col;

    // per-lane stream bases (sequential in b)
    const float4* xt4 = (const float4*)x2t + (size_t)blockIdx.x * 4096 + col * 2;
    const int*    dtp = dones_t + (size_t)blockIdx.x * (B_DIM * 8) + col;

    // gate weights: rows j, 8+j, 16+j, 24+j of Wih / Whh
    float wI[8], wF[8], wG[8], wO[8], uI[8], uF[8], uG[8], uO[8];
#pragma unroll
    for (int k = 0; k < 8; ++k) {
        wI[k] = Wih[j * 8 + k];        uI[k] = Whh[j * 8 + k];
        wF[k] = Wih[(8 + j) * 8 + k];  uF[k] = Whh[(8 + j) * 8 + k];
        wG[k] = Wih[(16 + j) * 8 + k]; uG[k] = Whh[(16 + j) * 8 + k];
        wO[k] = Wih[(24 + j) * 8 + k]; uO[k] = Whh[(24 + j) * 8 + k];
    }
    float bI = bih[j]      + bhh[j];
    float bF = bih[8 + j]  + bhh[8 + j];
    float bG = bih[16 + j] + bhh[16 + j];
    float bO = bih[24 + j] + bhh[24 + j];

    // head weights
    float hw0[8], hw1[8], hw2[8];
    float hb0 = ba[j], hb1 = ba[8 + j], hb2 = 0.f;
#pragma unroll
    for (int k = 0; k < 8; ++k) {
        hw0[k] = Wa[j * 8 + k];
        hw1[k] = Wa[(8 + j) * 8 + k];
        hw2[k] = 0.f;
    }
    if (j < 2) {
#pragma unroll
        for (int k = 0; k < 8; ++k) hw2[k] = Wa[(16 + j) * 8 + k];
        hb2 = ba[16 + j];
    } else if (j == 2) {
#pragma unroll
        for (int k = 0; k < 8; ++k) hw2[k] = Wv[k];
        hb2 = bv[0];
    }

    // initial carry: h = hx[0][t][:], c = hx[1][t][j]
    float h[8];
#pragma unroll
    for (int k = 0; k < 8; ++k) h[k] = hx[t * 8 + k];
    float c = hx[T_DIM * 8 + t * 8 + j];

    float* outA = out + (size_t)t * 18;                       // (b*T+t)*18, b=0
    float* outV = out + (size_t)18 * B_DIM * T_DIM + t;       // values block

    // 8-deep prefetch (named registers, unconditional)
    int dn0, dn1, dn2, dn3, dn4, dn5, dn6, dn7;
    float4 xa0, xb0, xa1, xb1, xa2, xb2, xa3, xb3;
    float4 xa4, xb4, xa5, xb5, xa6, xb6, xa7, xb7;
#define PF(I) \
    dn##I = dtp[(I) * 8]; \
    xa##I = xt4[(size_t)(I) * 16]; xb##I = xt4[(size_t)(I) * 16 + 1];
    PF(0) PF(1) PF(2) PF(3) PF(4) PF(5) PF(6) PF(7)
#undef PF

#define LSTM_STEP(BCUR, DPF, XA, XB)                                           \
    {                                                                          \
        int   done = DPF;                                                      \
        float4 va = XA, vb = XB;                                               \
        int bp = (BCUR) + 8; bp = (bp > B_DIM - 1) ? (B_DIM - 1) : bp;         \
        DPF = dtp[bp * 8];                                                     \
        XA = xt4[(size_t)bp * 16];                                             \
        XB = xt4[(size_t)bp * 16 + 1];                                         \
        /* x-part of the 4 gates (independent chains) */                       \
        float gi = bI, gf = bF, gg = bG, go = bO;                              \
        gi = fmaf(va.x, wI[0], gi); gi = fmaf(va.y, wI[1], gi);                \
        gi = fmaf(va.z, wI[2], gi); gi = fmaf(va.w, wI[3], gi);                \
        gi = fmaf(vb.x, wI[4], gi); gi = fmaf(vb.y, wI[5], gi);                \
        gi = fmaf(vb.z, wI[6], gi); gi = fmaf(vb.w, wI[7], gi);                \
        gf = fmaf(va.x, wF[0], gf); gf = fmaf(va.y, wF[1], gf);                \
        gf = fmaf(va.z, wF[2], gf); gf = fmaf(va.w, wF[3], gf);                \
        gf = fmaf(vb.x, wF[4], gf); gf = fmaf(vb.y, wF[5], gf);                \
        gf = fmaf(vb.z, wF[6], gf); gf = fmaf(vb.w, wF[7], gf);                \
        gg = fmaf(va.x, wG[0], gg); gg = fmaf(va.y, wG[1], gg);                \
        gg = fmaf(va.z, wG[2], gg); gg = fmaf(va.w, wG[3], gg);                \
        gg = fmaf(vb.x, wG[4], gg); gg = fmaf(vb.y, wG[5], gg);                \
        gg = fmaf(vb.z, wG[6], gg); gg = fmaf(vb.w, wG[7], gg);                \
        go = fmaf(va.x, wO[0], go); go = fmaf(va.y, wO[1], go);                \
        go = fmaf(va.z, wO[2], go); go = fmaf(va.w, wO[3], go);                \
        go = fmaf(vb.x, wO[4], go); go = fmaf(vb.y, wO[5], go);                \
        go = fmaf(vb.z, wO[6], go); go = fmaf(vb.w, wO[7], go);                \
        /* h-part */                                                           \
        float dI = h[0] * uI[0], dF = h[0] * uF[0];                            \
        float dG = h[0] * uG[0], dO = h[0] * uO[0];                            \
        dI = fmaf(h[1], uI[1], dI); dF = fmaf(h[1], uF[1], dF);                \
        dG = fmaf(h[1], uG[1], dG); dO = fmaf(h[1], uO[1], dO);                \
        dI = fmaf(h[2], uI[2], dI); dF = fmaf(h[2], uF[2], dF);                \
        dG = fmaf(h[2], uG[2], dG); dO = fmaf(h[2], uO[2], dO);                \
        dI = fmaf(h[3], uI[3], dI); dF = fmaf(h[3], uF[3], dF);                \
        dG = fmaf(h[3], uG[3], dG); dO = fmaf(h[3], uO[3], dO);                \
        dI = fmaf(h[4], uI[4], dI); dF = fmaf(h[4], uF[4], dF);                \
        dG = fmaf(h[4], uG[4], dG); dO = fmaf(h[4], uO[4], dO);                \
        dI = fmaf(h[5], uI[5], dI); dF = fmaf(h[5], uF[5], dF);                \
        dG = fmaf(h[5], uG[5], dG); dO = fmaf(h[5], uO[5], dO);                \
        dI = fmaf(h[6], uI[6], dI); dF = fmaf(h[6], uF[6], dF);                \
        dG = fmaf(h[6], uG[6], dG); dO = fmaf(h[6], uO[6], dO);                \
        dI = fmaf(h[7], uI[7], dI); dF = fmaf(h[7], uF[7], dF);                \
        dG = fmaf(h[7], uG[7], dG); dO = fmaf(h[7], uO[7], dO);                \
        float GI = done ? gi : (gi + dI);                                      \
        float GF = done ? gf : (gf + dF);                                      \
        float GG = done ? gg : (gg + dG);                                      \
        float GO = done ? go : (go + dO);                                      \
        c = done ? 0.f : c;                                                    \
        float i_ = 1.f / (1.f + __expf(-GI));                                  \
        float f_ = 1.f / (1.f + __expf(-GF));                                  \
        float g_ = 2.f / (1.f + __expf(-2.f * GG)) - 1.f;                      \
        float o_ = 1.f / (1.f + __expf(-GO));                                  \
        float c2 = fmaf(f_, c, i_ * g_);                                       \
        c = c2;                                                                \
        float th = 2.f / (1.f + __expf(-2.f * c2)) - 1.f;                      \
        float h2 = o_ * th;                                                    \
        h[0] = __shfl(h2, gb | 0, 64);                                         \
        h[1] = __shfl(h2, gb | 1, 64);                                         \
        h[2] = __shfl(h2, gb | 2, 64);                                         \
        h[3] = __shfl(h2, gb | 3, 64);                                         \
        h[4] = __shfl(h2, gb | 4, 64);                                         \
        h[5] = __shfl(h2, gb | 5, 64);                                         \
        h[6] = __shfl(h2, gb | 6, 64);                                         \
        h[7] = __shfl(h2, gb | 7, 64);                                         \
        float o0 = hb0, o1 = hb1, o2 = hb2;                                    \
        o0 = fmaf(h[0], hw0[0], o0); o1 = fmaf(h[0], hw1[0], o1);              \
        o2 = fmaf(h[0], hw2[0], o2);                                           \
        o0 = fmaf(h[1], hw0[1], o0); o1 = fmaf(h[1], hw1[1], o1);              \
        o2 = fmaf(h[1], hw2[1], o2);                                           \
        o0 = fmaf(h[2], hw0[2], o0); o1 = fmaf(h[2], hw1[2], o1);              \
        o2 = fmaf(h[2], hw2[2], o2);                                           \
        o0 = fmaf(h[3], hw0[3], o0); o1 = fmaf(h[3], hw1[3], o1);              \
        o2 = fmaf(h[3], hw2[3], o2);                                           \
        o0 = fmaf(h[4], hw0[4], o0); o1 = fmaf(h[4], hw1[4], o1);              \
        o2 = fmaf(h[4], hw2[4], o2);                                           \
        o0 = fmaf(h[5], hw0[5], o0); o1 = fmaf(h[5], hw1[5], o1);              \
        o2 = fmaf(h[5], hw2[5], o2);                                           \
        o0 = fmaf(h[6], hw0[6], o0); o1 = fmaf(h[6], hw1[6], o1);              \
        o2 = fmaf(h[6], hw2[6], o2);                                           \
        o0 = fmaf(h[7], hw0[7], o0); o1 = fmaf(h[7], hw1[7], o1);              \
        o2 = fmaf(h[7], hw2[7], o2);                                           \
        outA[j] = o0;                                                          \
        outA[8 + j] = o1;                                                      \
        if (j < 2) outA[16 + j] = o2;                                          \
        else if (j == 2) *outV = o2;                                           \
        outA += (size_t)T_DIM * 18;                                            \
        outV += T_DIM;                                                         \
    }

    for (int b0 = 0; b0 < B_DIM; b0 += 8) {
        LSTM_STEP(b0 + 0, dn0, xa0, xb0);
        LSTM_STEP(b0 + 1, dn1, xa1, xb1);
        LSTM_STEP(b0 + 2, dn2, xa2, xb2);
        LSTM_STEP(b0 + 3, dn3, xa3, xb3);
        LSTM_STEP(b0 + 4, dn4, xa4, xb4);
        LSTM_STEP(b0 + 5, dn5, xa5, xb5);
        LSTM_STEP(b0 + 6, dn6, xa6, xb6);
        LSTM_STEP(b0 + 7, dn7, xa7, xb7);
    }
#undef LSTM_STEP
}

// ---------------------------------------------------------------------------
extern "C" void kernel_launch(void* const* d_in, const int* in_sizes, int n_in,
                              void* d_out, int out_size, void* d_ws, size_t ws_size,
                              hipStream_t stream) {
    (void)in_sizes; (void)n_in; (void)out_size; (void)ws_size;
    const float* states = (const float*)d_in[0];
    const int*   dones  = (const int*)d_in[1];
    const float* hx     = (const float*)d_in[2];
    const float* W1     = (const float*)d_in[3];
    const float* b1     = (const float*)d_in[4];
    const float* W2     = (const float*)d_in[5];
    const float* b2     = (const float*)d_in[6];
    const float* Wih    = (const float*)d_in[7];
    const float* bih    = (const float*)d_in[8];
    const float* Whh    = (const float*)d_in[9];
    const float* bhh    = (const float*)d_in[10];
    const float* Wa     = (const float*)d_in[11];
    const float* ba     = (const float*)d_in[12];
    const float* Wv     = (const float*)d_in[13];
    const float* bv     = (const float*)d_in[14];
    float* out = (float*)d_out;
    float* x2t     = (float*)d_ws;                      // 32 MiB
    int*   dones_t = (int*)((char*)d_ws + (size_t)X2T_FLOATS * 4); // 4 MiB

    mlp_kernel<<<(B_DIM * T_DIM) / 64, 256, 0, stream>>>(states, dones, W1, b1, W2, b2,
                                                         x2t, dones_t);
    lstm_head_kernel<<<T_DIM / 8, 64, 0, stream>>>(x2t, dones_t, hx, Wih, bih, Whh, bhh,
                                                   Wa, ba, Wv, bv, out);
}